// Round 2
// baseline (6676.029 us; speedup 1.0000x reference)
//
#include <hip/hip_runtime.h>

#define B_SZ   2048
#define ILEN   64
#define CLEN   128
#define NCH    256
#define L0_    127
#define L1_    125
#define L2_    123
#define L3_    121
#define F1_    512
#define FCK    30976
#define SPLIT  32
#define KCH    968          // 30976 / 32
#define KPS    31           // ceil(968/32)

// ---------------------------------------------------------------------------
// Prep: transpose conv weights W[co][ci][k] -> Wt[(ci*3+k)*256 + co]
// ---------------------------------------------------------------------------
__global__ __launch_bounds__(256) void wtrans_kernel(const float* __restrict__ W,
                                                     float* __restrict__ Wt) {
    int idx = blockIdx.x * 256 + threadIdx.x;
    if (idx >= NCH * 3 * NCH) return;
    int co = idx & 255;
    int r  = idx >> 8;          // ci*3 + k
    int k  = r % 3;
    int ci = r / 3;
    Wt[idx] = W[((size_t)co * NCH + ci) * 3 + k];
}

// ---------------------------------------------------------------------------
// Pointwise layer: h0[b,c,l] = relu( x0·Wp0[c] + x[(l+1)*64..]·Wp1[c] + bp[c] )
// One block per (chunk-local) b, 128 threads.
// ---------------------------------------------------------------------------
__global__ __launch_bounds__(128) void pointwise_kernel(const float* __restrict__ x,
                                                        const float* __restrict__ Wp,
                                                        const float* __restrict__ bp,
                                                        float* __restrict__ h0) {
    __shared__ float d0s[NCH];
    const int b   = blockIdx.x;
    const int tid = threadIdx.x;
    const float* xrow = x + (size_t)b * (CLEN * ILEN);

    // phase 1: per-channel l=0 dot (2 channels per thread)
    for (int cc = 0; cc < 2; ++cc) {
        int c = tid + cc * 128;
        float d0 = bp[c];
        const float4* wp4 = (const float4*)(Wp + (size_t)c * 128);
#pragma unroll
        for (int j4 = 0; j4 < 32; ++j4) {
            float4 v = wp4[j4];                 // (w0[2j],w1[2j],w0[2j+1],w1[2j+1])
            d0 = fmaf(xrow[2 * j4], v.x, d0);
            d0 = fmaf(xrow[2 * j4 + 1], v.z, d0);
        }
        d0s[c] = d0;
    }
    __syncthreads();

    // phase 2: thread = output position l
    const int l = tid;
    if (l < L0_) {
        float xw[64];
        const float4* xr4 = (const float4*)(xrow + (size_t)(l + 1) * 64);
#pragma unroll
        for (int j4 = 0; j4 < 16; ++j4) {
            float4 v = xr4[j4];
            xw[4 * j4 + 0] = v.x; xw[4 * j4 + 1] = v.y;
            xw[4 * j4 + 2] = v.z; xw[4 * j4 + 3] = v.w;
        }
        float* outb = h0 + (size_t)b * NCH * L0_ + l;
        for (int c = 0; c < NCH; ++c) {
            float acc = d0s[c];
            const float4* wp4 = (const float4*)(Wp + (size_t)c * 128);
#pragma unroll
            for (int j4 = 0; j4 < 32; ++j4) {
                float4 v = wp4[j4];
                acc = fmaf(xw[2 * j4], v.y, acc);
                acc = fmaf(xw[2 * j4 + 1], v.w, acc);
            }
            outb[(size_t)c * L0_] = fmaxf(acc, 0.f);
        }
    }
}

// ---------------------------------------------------------------------------
// Conv layer (implicit GEMM). Block = (local b, 64-co tile), 256 threads.
// Thread tile: 4 co x 8 l. K-loop: 8 chunks of 32 ci.
// ---------------------------------------------------------------------------
template <int LIN, int LOUT>
__global__ __launch_bounds__(256) void conv_kernel(const float* __restrict__ hin,
                                                   const float* __restrict__ wt,
                                                   const float* __restrict__ bias,
                                                   float* __restrict__ hout) {
    __shared__ float ins[32][132];     // ci x l (padded)
    __shared__ float wgt[32][3][64];   // ci x k x co

    const int b    = blockIdx.x;
    const int co0  = blockIdx.y * 64;
    const int tid  = threadIdx.x;
    const int co_t = tid & 15;
    const int l0   = (tid >> 4) * 8;

    float acc[4][8];
#pragma unroll
    for (int i = 0; i < 4; ++i)
#pragma unroll
        for (int j = 0; j < 8; ++j) acc[i][j] = 0.f;

    for (int ch = 0; ch < 8; ++ch) {
        const int ci0 = ch * 32;
        __syncthreads();
        for (int idx = tid; idx < 32 * LIN; idx += 256) {
            int ci = idx / LIN;
            int l  = idx - ci * LIN;
            ins[ci][l] = hin[((size_t)b * NCH + ci0 + ci) * LIN + l];
        }
        for (int idx = tid; idx < 32 * 3 * 64; idx += 256) {
            (&wgt[0][0][0])[idx] = wt[((size_t)ci0 * 3) * NCH + (size_t)(idx >> 6) * NCH
                                      + co0 + (idx & 63)];
        }
        __syncthreads();

        for (int ci = 0; ci < 32; ++ci) {
            float xw[10];
            float4 xa = *(const float4*)&ins[ci][l0];
            float4 xb = *(const float4*)&ins[ci][l0 + 4];
            xw[0] = xa.x; xw[1] = xa.y; xw[2] = xa.z; xw[3] = xa.w;
            xw[4] = xb.x; xw[5] = xb.y; xw[6] = xb.z; xw[7] = xb.w;
            xw[8] = ins[ci][l0 + 8];
            xw[9] = ins[ci][l0 + 9];
#pragma unroll
            for (int k = 0; k < 3; ++k) {
                float4 w4 = *(const float4*)&wgt[ci][k][co_t * 4];
#pragma unroll
                for (int li = 0; li < 8; ++li) {
                    float xv = xw[li + k];
                    acc[0][li] = fmaf(w4.x, xv, acc[0][li]);
                    acc[1][li] = fmaf(w4.y, xv, acc[1][li]);
                    acc[2][li] = fmaf(w4.z, xv, acc[2][li]);
                    acc[3][li] = fmaf(w4.w, xv, acc[3][li]);
                }
            }
        }
    }

#pragma unroll
    for (int i = 0; i < 4; ++i) {
        int co = co0 + co_t * 4 + i;
        float bv = bias[co];
        float* op = hout + ((size_t)b * NCH + co) * LOUT + l0;
#pragma unroll
        for (int li = 0; li < 8; ++li) {
            if (l0 + li < LOUT) op[li] = fmaxf(acc[i][li] + bv, 0.f);
        }
    }
}

// ---------------------------------------------------------------------------
// FC1: part[sp][m][n] = sum over split sp's K-range of A[m][k]*Wf1[n][k]
// Block tile 128x128, K-chunk 32, thread tile 8x8 strided by 16. M = CB.
// ---------------------------------------------------------------------------
__global__ __launch_bounds__(256) void fc1_kernel(const float* __restrict__ A,
                                                  const float* __restrict__ Bw,
                                                  float* __restrict__ part,
                                                  int CB) {
    __shared__ float As[128][33];
    __shared__ float Bs[128][33];
    const int m0  = blockIdx.x * 128;
    const int n0  = blockIdx.y * 128;
    const int sp  = blockIdx.z;
    const int tid = threadIdx.x;
    const int mt  = tid & 15;
    const int nt  = tid >> 4;
    const int start = sp * KPS;
    const int kc    = min(KPS, KCH - start);

    float acc[8][8];
#pragma unroll
    for (int i = 0; i < 8; ++i)
#pragma unroll
        for (int j = 0; j < 8; ++j) acc[i][j] = 0.f;

    for (int ch = 0; ch < kc; ++ch) {
        const int k0 = (start + ch) * 32;
        __syncthreads();
#pragma unroll
        for (int i = 0; i < 4; ++i) {
            int idx = tid + i * 256;
            int row = idx >> 3;
            int c4  = (idx & 7) << 2;
            float4 v = *(const float4*)&A[(size_t)(m0 + row) * FCK + k0 + c4];
            As[row][c4 + 0] = v.x; As[row][c4 + 1] = v.y;
            As[row][c4 + 2] = v.z; As[row][c4 + 3] = v.w;
            float4 w = *(const float4*)&Bw[(size_t)(n0 + row) * FCK + k0 + c4];
            Bs[row][c4 + 0] = w.x; Bs[row][c4 + 1] = w.y;
            Bs[row][c4 + 2] = w.z; Bs[row][c4 + 3] = w.w;
        }
        __syncthreads();

        for (int kk = 0; kk < 32; ++kk) {
            float av[8], bv[8];
#pragma unroll
            for (int i = 0; i < 8; ++i) av[i] = As[mt + 16 * i][kk];
#pragma unroll
            for (int j = 0; j < 8; ++j) bv[j] = Bs[nt + 16 * j][kk];
#pragma unroll
            for (int i = 0; i < 8; ++i)
#pragma unroll
                for (int j = 0; j < 8; ++j)
                    acc[i][j] = fmaf(av[i], bv[j], acc[i][j]);
        }
    }

#pragma unroll
    for (int i = 0; i < 8; ++i)
#pragma unroll
        for (int j = 0; j < 8; ++j)
            part[((size_t)sp * CB + m0 + mt + 16 * i) * F1_ + n0 + nt + 16 * j] =
                acc[i][j];
}

// h4[m,f] = relu(bf1[f] + sum_sp part[sp][m][f]), m chunk-local
__global__ __launch_bounds__(256) void fc1_reduce_kernel(const float* __restrict__ part,
                                                         const float* __restrict__ bf1,
                                                         float* __restrict__ h4,
                                                         int CB) {
    int idx = blockIdx.x * 256 + threadIdx.x;   // < CB*512
    int f = idx & (F1_ - 1);
    float s = bf1[f];
#pragma unroll
    for (int sp = 0; sp < SPLIT; ++sp)
        s += part[((size_t)sp * CB) * F1_ + idx];
    h4[idx] = fmaxf(s, 0.f);
}

// out[b] = bf2 + h4[b,:] . Wf2
__global__ __launch_bounds__(256) void fc2_kernel(const float* __restrict__ h4,
                                                  const float* __restrict__ Wf2,
                                                  const float* __restrict__ bf2,
                                                  float* __restrict__ out) {
    const int b    = blockIdx.x * 4 + (threadIdx.x >> 6);
    const int lane = threadIdx.x & 63;
    float s = 0.f;
#pragma unroll
    for (int i = 0; i < 8; ++i) s = fmaf(h4[(size_t)b * F1_ + lane + 64 * i],
                                         Wf2[lane + 64 * i], s);
#pragma unroll
    for (int o = 32; o > 0; o >>= 1) s += __shfl_xor(s, o);
    if (lane == 0) out[b] = s + bf2[0];
}

// ---------------------------------------------------------------------------
extern "C" void kernel_launch(void* const* d_in, const int* in_sizes, int n_in,
                              void* d_out, int out_size, void* d_ws, size_t ws_size,
                              hipStream_t stream) {
    const float* x   = (const float*)d_in[0];
    const float* Wp  = (const float*)d_in[1];
    const float* bp  = (const float*)d_in[2];
    const float* W1  = (const float*)d_in[3];
    const float* b1  = (const float*)d_in[4];
    const float* W2  = (const float*)d_in[5];
    const float* b2  = (const float*)d_in[6];
    const float* W3  = (const float*)d_in[7];
    const float* b3  = (const float*)d_in[8];
    const float* Wf1 = (const float*)d_in[9];
    const float* bf1 = (const float*)d_in[10];
    const float* Wf2 = (const float*)d_in[11];
    const float* bf2 = (const float*)d_in[12];
    float* out = (float*)d_out;

    // ---- adaptive chunking from ws_size --------------------------------
    const size_t WT     = (size_t)NCH * 3 * NCH;          // 196,608 floats
    const size_t H4SZ   = (size_t)B_SZ * F1_;             // 1,048,576 floats
    const size_t PERSIS = 3 * WT + H4SZ;                  // 1,638,400 floats
    // per-chunk floats: buf0 CB*32512, buf1 CB*32000, part CB*16384
    const size_t PERB   = 32512 + 32000 + 16384;          // 80,896 floats / b

    int CB = 0;
    const int cand[5] = {2048, 1024, 512, 256, 128};
    for (int i = 0; i < 5; ++i) {
        size_t tot = (PERSIS + (size_t)cand[i] * PERB) * sizeof(float);
        if (tot <= ws_size) { CB = cand[i]; break; }
    }
    if (CB == 0) return;   // < 48 MB scratch: fail visibly
    const int nchunk = B_SZ / CB;

    float* ws   = (float*)d_ws;
    float* wt1  = ws;
    float* wt2  = wt1 + WT;
    float* wt3  = wt2 + WT;
    float* h4   = wt3 + WT;                       // 2048 x 512 (persistent)
    float* part = h4 + H4SZ;                      // SPLIT x CB x 512
    float* buf0 = part + (size_t)SPLIT * CB * F1_;
    float* buf1 = buf0 + (size_t)CB * NCH * L0_;

    // weight transposes (once)
    wtrans_kernel<<<768, 256, 0, stream>>>(W1, wt1);
    wtrans_kernel<<<768, 256, 0, stream>>>(W2, wt2);
    wtrans_kernel<<<768, 256, 0, stream>>>(W3, wt3);

    for (int c = 0; c < nchunk; ++c) {
        const float* xc = x + (size_t)c * CB * (CLEN * ILEN);
        pointwise_kernel<<<CB, 128, 0, stream>>>(xc, Wp, bp, buf0);
        conv_kernel<L0_, L1_><<<dim3(CB, 4), 256, 0, stream>>>(buf0, wt1, b1, buf1);
        conv_kernel<L1_, L2_><<<dim3(CB, 4), 256, 0, stream>>>(buf1, wt2, b2, buf0);
        conv_kernel<L2_, L3_><<<dim3(CB, 4), 256, 0, stream>>>(buf0, wt3, b3, buf1);
        fc1_kernel<<<dim3(CB / 128, 4, SPLIT), 256, 0, stream>>>(buf1, Wf1, part, CB);
        fc1_reduce_kernel<<<CB * 2, 256, 0, stream>>>(part, bf1,
                                                      h4 + (size_t)c * CB * F1_, CB);
    }

    fc2_kernel<<<B_SZ / 4, 256, 0, stream>>>(h4, Wf2, bf2, out);
}

// Round 3
// 1214.712 us; speedup vs baseline: 5.4960x; 5.4960x over previous
//
#include <hip/hip_runtime.h>

typedef _Float16 f16;
typedef _Float16 f16x8 __attribute__((ext_vector_type(8)));
typedef _Float16 f16x4 __attribute__((ext_vector_type(4)));
typedef float    f32x4 __attribute__((ext_vector_type(4)));

#define B_SZ   2048
#define CLEN   128
#define NCH    256
#define L0_    127
#define L1_    125
#define L2_    123
#define L3_    121
#define F1_    512
#define FCK    30976
#define SPLIT  22          // 968 K-chunks of 32 -> 44 per split
#define CPS    44

// ---------------------------------------------------------------------------
// prep: Wp[:, :, 1] -> fp16 wp1t[c][j]   (16384 elems)
// ---------------------------------------------------------------------------
__global__ __launch_bounds__(256) void prep_wp1t(const float* __restrict__ Wp,
                                                 f16* __restrict__ wp1t) {
    int idx = blockIdx.x * 256 + threadIdx.x;
    if (idx >= NCH * 64) return;
    int c = idx >> 6, j = idx & 63;
    wp1t[idx] = (f16)Wp[c * 128 + j * 2 + 1];
}

// prep: W[co][ci][k] -> fp16 wct[co][k*256+ci]   (196608 elems)
__global__ __launch_bounds__(256) void prep_wct(const float* __restrict__ W,
                                                f16* __restrict__ wct) {
    int idx = blockIdx.x * 256 + threadIdx.x;
    if (idx >= NCH * 768) return;
    int co = idx / 768, rem = idx - co * 768;
    int k = rem >> 8, ci = rem & 255;
    wct[idx] = (f16)W[((size_t)co * NCH + ci) * 3 + k];
}

// prep: straight fp32->fp16 cast of Wf1 (512 x 30976), vectorized x4
__global__ __launch_bounds__(256) void prep_wf1h(const float* __restrict__ Wf1,
                                                 f16* __restrict__ wf1h) {
    size_t g = (size_t)blockIdx.x * 256 + threadIdx.x;
    if (g * 4 >= (size_t)F1_ * FCK) return;
    float4 v = *(const float4*)(Wf1 + g * 4);
    f16x4 h = { (f16)v.x, (f16)v.y, (f16)v.z, (f16)v.w };
    *(f16x4*)(wf1h + g * 4) = h;
}

// prep: x -> fp16 xh (2048*8192), + zero 64-elem pad
__global__ __launch_bounds__(256) void prep_xh(const float* __restrict__ x,
                                               f16* __restrict__ xh) {
    size_t g = (size_t)blockIdx.x * 256 + threadIdx.x;
    size_t N = (size_t)B_SZ * 8192;
    if (g * 4 >= N + 64) return;
    if (g * 4 < N) {
        float4 v = *(const float4*)(x + g * 4);
        f16x4 h = { (f16)v.x, (f16)v.y, (f16)v.z, (f16)v.w };
        *(f16x4*)(xh + g * 4) = h;
    } else {
        f16x4 z = { (f16)0.f, (f16)0.f, (f16)0.f, (f16)0.f };
        *(f16x4*)(xh + g * 4) = z;
    }
}

// ---------------------------------------------------------------------------
// d0[b][c] = bp[c] + sum_j x[b][j] * Wp[c][j][0]   (fp32, exact path)
// ---------------------------------------------------------------------------
__global__ __launch_bounds__(256) void d0_kernel(const float* __restrict__ x,
                                                 const float* __restrict__ Wp,
                                                 const float* __restrict__ bp,
                                                 float* __restrict__ d0) {
    __shared__ float wp0s[NCH * 65];
    __shared__ float x0[64];
    const int b = blockIdx.x, tid = threadIdx.x;
    for (int u = tid; u < NCH * 64; u += 256) {
        int c = u >> 6, j = u & 63;
        wp0s[c * 65 + j] = Wp[c * 128 + j * 2];
    }
    if (tid < 64) x0[tid] = x[(size_t)b * 8192 + tid];
    __syncthreads();
    const int c = tid;
    float acc = bp[c];
#pragma unroll
    for (int j = 0; j < 64; ++j) acc = fmaf(x0[j], wp0s[c * 65 + j], acc);
    d0[(size_t)b * NCH + c] = acc;
}

// ---------------------------------------------------------------------------
// Unified MFMA layer: out[b][l][co] = relu(extra + sum_{k,ci} in[b][l+k][ci]*W)
//  - block = one b, 256 threads (4 waves, 2x2 of 64l x 128co)
//  - A (activations) from padded LDS; B (weights [co][KT]) from global
//  - D layout (verified): row l = (lane>>4)*4+reg, col co = lane&15
// ---------------------------------------------------------------------------
template <int SROWS, int LOUT, int CIN, int KT, int PADC>
__global__ __launch_bounds__(256, 2) void mfma_layer(const f16* __restrict__ in,
                                                     long in_bstride,
                                                     const f16* __restrict__ wt,
                                                     const float* __restrict__ extra,
                                                     long e_bstride,
                                                     f16* __restrict__ out) {
    __shared__ f16 ins[130 * PADC];
    const int b = blockIdx.x;
    const int tid = threadIdx.x;
    const int lane = tid & 63, w = tid >> 6;
    const int wl0 = (w >> 1) * 64, wc0 = (w & 1) * 128;
    const int lr = lane & 15, lh = lane >> 4;

    // stage input tile (contiguous rows of CIN fp16)
    const f16* inb = in + (size_t)b * in_bstride;
    constexpr int UPR = CIN / 8;             // 16B units per row
    constexpr int USH = (CIN == 256) ? 5 : 3;
    constexpr int UMS = UPR - 1;
    for (int u = tid; u < SROWS * UPR; u += 256) {
        int row = u >> USH, sl = u & UMS;
        *(f16x8*)(ins + row * PADC + sl * 8) =
            *(const f16x8*)(inb + (size_t)row * CIN + sl * 8);
    }
    __syncthreads();

    f32x4 acc[4][8];
#pragma unroll
    for (int m = 0; m < 4; ++m)
#pragma unroll
        for (int n = 0; n < 8; ++n) acc[m][n] = (f32x4){0.f, 0.f, 0.f, 0.f};

    constexpr int KSTEPS = KT / 32;
    constexpr int CSTEPS = CIN / 32;
    for (int ks = 0; ks < KSTEPS; ++ks) {
        const int k = ks / CSTEPS;
        const int ci0 = (ks % CSTEPS) * 32;
        f16x8 a[4];
#pragma unroll
        for (int m = 0; m < 4; ++m)
            a[m] = *(const f16x8*)(ins + (wl0 + 16 * m + lr + k) * PADC + ci0 + lh * 8);
#pragma unroll
        for (int n = 0; n < 8; ++n) {
            f16x8 bf = *(const f16x8*)(wt + (size_t)(wc0 + 16 * n + lr) * KT
                                       + ks * 32 + lh * 8);
#pragma unroll
            for (int m = 0; m < 4; ++m)
                acc[m][n] = __builtin_amdgcn_mfma_f32_16x16x32_f16(a[m], bf,
                                                                   acc[m][n], 0, 0, 0);
        }
    }

    // epilogue: +extra, relu, fp16 store to [b][l][256]
    const float* ep = extra + (size_t)b * e_bstride;
    f16* ob = out + (size_t)b * LOUT * NCH;
#pragma unroll
    for (int n = 0; n < 8; ++n) {
        const int co = wc0 + 16 * n + lr;
        const float e = ep[co];
#pragma unroll
        for (int m = 0; m < 4; ++m) {
#pragma unroll
            for (int r = 0; r < 4; ++r) {
                const int l = wl0 + 16 * m + lh * 4 + r;
                if (l < LOUT) {
                    float v = fmaxf(acc[m][n][r] + e, 0.f);
                    ob[(size_t)l * NCH + co] = (f16)v;
                }
            }
        }
    }
}

// ---------------------------------------------------------------------------
// h3 [b][121][256] -> h3t [b][co*121+l]  (FC-ready, matches Wf1 kappa order)
// ---------------------------------------------------------------------------
__global__ __launch_bounds__(256) void h3t_kernel(const f16* __restrict__ h3,
                                                  f16* __restrict__ h3t) {
    __shared__ f16 t[L3_ * 264];
    const int b = blockIdx.x, tid = threadIdx.x;
    for (int u = tid; u < L3_ * 32; u += 256) {
        int row = u >> 5, sl = u & 31;
        *(f16x8*)(t + row * 264 + sl * 8) =
            *(const f16x8*)(h3 + (size_t)b * FCK + u * 8);
    }
    __syncthreads();
    const int co = tid;
    f16* ob = h3t + (size_t)b * FCK + (size_t)co * L3_;
    for (int l = 0; l < L3_; ++l) ob[l] = t[l * 264 + co];
}

// ---------------------------------------------------------------------------
// FC1 MFMA: part[sp][b_local][f] over split sp's K-range (fp32 partials)
// tile 128b x 128f, K-chunk 32, 4 waves 2x2 of 64x64
// ---------------------------------------------------------------------------
__global__ __launch_bounds__(256, 2) void fc1_kernel(const f16* __restrict__ A,
                                                     const f16* __restrict__ Bw,
                                                     float* __restrict__ part,
                                                     int CB) {
    __shared__ f16 As[128 * 40];
    __shared__ f16 Bs[128 * 40];
    const int m0 = blockIdx.x * 128, n0 = blockIdx.y * 128, sp = blockIdx.z;
    const int tid = threadIdx.x;
    const int lane = tid & 63, w = tid >> 6;
    const int wb0 = (w >> 1) * 64, wf0 = (w & 1) * 64;
    const int lr = lane & 15, lh = lane >> 4;

    f32x4 acc[4][4];
#pragma unroll
    for (int m = 0; m < 4; ++m)
#pragma unroll
        for (int n = 0; n < 4; ++n) acc[m][n] = (f32x4){0.f, 0.f, 0.f, 0.f};

    for (int it = 0; it < CPS; ++it) {
        const int k0 = (sp * CPS + it) * 32;
        __syncthreads();
        for (int u = tid; u < 512; u += 256) {
            int row = u >> 2, sl = u & 3;
            *(f16x8*)(As + row * 40 + sl * 8) =
                *(const f16x8*)(A + (size_t)(m0 + row) * FCK + k0 + sl * 8);
            *(f16x8*)(Bs + row * 40 + sl * 8) =
                *(const f16x8*)(Bw + (size_t)(n0 + row) * FCK + k0 + sl * 8);
        }
        __syncthreads();
        f16x8 a[4], bf[4];
#pragma unroll
        for (int m = 0; m < 4; ++m)
            a[m] = *(const f16x8*)(As + (wb0 + 16 * m + lr) * 40 + lh * 8);
#pragma unroll
        for (int n = 0; n < 4; ++n)
            bf[n] = *(const f16x8*)(Bs + (wf0 + 16 * n + lr) * 40 + lh * 8);
#pragma unroll
        for (int m = 0; m < 4; ++m)
#pragma unroll
            for (int n = 0; n < 4; ++n)
                acc[m][n] = __builtin_amdgcn_mfma_f32_16x16x32_f16(a[m], bf[n],
                                                                   acc[m][n], 0, 0, 0);
    }

#pragma unroll
    for (int m = 0; m < 4; ++m)
#pragma unroll
        for (int n = 0; n < 4; ++n)
#pragma unroll
            for (int r = 0; r < 4; ++r) {
                const int bl = m0 + wb0 + 16 * m + lh * 4 + r;
                const int f  = n0 + wf0 + 16 * n + lr;
                part[((size_t)sp * CB + bl) * F1_ + f] = acc[m][n][r];
            }
}

// h4[m,f] = relu(bf1[f] + sum_sp part[sp][m][f])
__global__ __launch_bounds__(256) void fc1_reduce_kernel(const float* __restrict__ part,
                                                         const float* __restrict__ bf1,
                                                         float* __restrict__ h4,
                                                         int CB) {
    int idx = blockIdx.x * 256 + threadIdx.x;
    int f = idx & (F1_ - 1);
    float s = bf1[f];
#pragma unroll
    for (int sp = 0; sp < SPLIT; ++sp)
        s += part[(size_t)sp * CB * F1_ + idx];
    h4[idx] = fmaxf(s, 0.f);
}

// out[b] = bf2 + h4[b,:] . Wf2   (fp32)
__global__ __launch_bounds__(256) void fc2_kernel(const float* __restrict__ h4,
                                                  const float* __restrict__ Wf2,
                                                  const float* __restrict__ bf2,
                                                  float* __restrict__ out) {
    const int b    = blockIdx.x * 4 + (threadIdx.x >> 6);
    const int lane = threadIdx.x & 63;
    float s = 0.f;
#pragma unroll
    for (int i = 0; i < 8; ++i) s = fmaf(h4[(size_t)b * F1_ + lane + 64 * i],
                                         Wf2[lane + 64 * i], s);
#pragma unroll
    for (int o = 32; o > 0; o >>= 1) s += __shfl_xor(s, o);
    if (lane == 0) out[b] = s + bf2[0];
}

// ---------------------------------------------------------------------------
extern "C" void kernel_launch(void* const* d_in, const int* in_sizes, int n_in,
                              void* d_out, int out_size, void* d_ws, size_t ws_size,
                              hipStream_t stream) {
    const float* x   = (const float*)d_in[0];
    const float* Wp  = (const float*)d_in[1];
    const float* bp  = (const float*)d_in[2];
    const float* W1  = (const float*)d_in[3];
    const float* b1  = (const float*)d_in[4];
    const float* W2  = (const float*)d_in[5];
    const float* b2  = (const float*)d_in[6];
    const float* W3  = (const float*)d_in[7];
    const float* b3  = (const float*)d_in[8];
    const float* Wf1 = (const float*)d_in[9];
    const float* bf1 = (const float*)d_in[10];
    const float* Wf2 = (const float*)d_in[11];
    const float* bf2 = (const float*)d_in[12];
    float* out = (float*)d_out;

    // ---- workspace layout (256B-aligned chunks) ------------------------
    char* base = (char*)d_ws;
    size_t off = 0;
    auto alloc = [&](size_t bytes) {
        size_t o = off; off = (off + bytes + 255) & ~(size_t)255; return o;
    };
    const size_t o_wp1t = alloc((size_t)NCH * 64 * 2);
    const size_t o_wct1 = alloc((size_t)NCH * 768 * 2);
    const size_t o_wct2 = alloc((size_t)NCH * 768 * 2);
    const size_t o_wct3 = alloc((size_t)NCH * 768 * 2);
    const size_t o_wf1h = alloc((size_t)F1_ * FCK * 2);
    const size_t o_xh   = alloc(((size_t)B_SZ * 8192 + 64) * 2);
    const size_t o_d0   = alloc((size_t)B_SZ * NCH * 4);
    const size_t o_h4   = alloc((size_t)B_SZ * F1_ * 4);
    const size_t fixed  = off;

    int CB = 0;
    const int cand[5] = {2048, 1024, 512, 256, 128};
    for (int i = 0; i < 5; ++i) {
        size_t c = (size_t)cand[i];
        size_t need = fixed
            + (((size_t)SPLIT * c * F1_ * 4 + 255) & ~(size_t)255)   // part
            + ((c * (size_t)L0_ * NCH * 2 + 255) & ~(size_t)255)     // buf0
            + ((c * (size_t)L1_ * NCH * 2 + 255) & ~(size_t)255);    // buf1
        if (need <= ws_size) { CB = cand[i]; break; }
    }
    if (CB == 0) return;
    const int nchunk = B_SZ / CB;

    const size_t o_part = alloc((size_t)SPLIT * CB * F1_ * 4);
    const size_t o_buf0 = alloc((size_t)CB * L0_ * NCH * 2);
    const size_t o_buf1 = alloc((size_t)CB * L1_ * NCH * 2);

    f16*   wp1t = (f16*)(base + o_wp1t);
    f16*   wct1 = (f16*)(base + o_wct1);
    f16*   wct2 = (f16*)(base + o_wct2);
    f16*   wct3 = (f16*)(base + o_wct3);
    f16*   wf1h = (f16*)(base + o_wf1h);
    f16*   xh   = (f16*)(base + o_xh);
    float* d0   = (float*)(base + o_d0);
    float* h4   = (float*)(base + o_h4);
    float* part = (float*)(base + o_part);
    f16*   buf0 = (f16*)(base + o_buf0);
    f16*   buf1 = (f16*)(base + o_buf1);

    // ---- preps ---------------------------------------------------------
    prep_wp1t<<<64, 256, 0, stream>>>(Wp, wp1t);
    prep_wct<<<768, 256, 0, stream>>>(W1, wct1);
    prep_wct<<<768, 256, 0, stream>>>(W2, wct2);
    prep_wct<<<768, 256, 0, stream>>>(W3, wct3);
    prep_wf1h<<<(int)(((size_t)F1_ * FCK / 4 + 255) / 256), 256, 0, stream>>>(Wf1, wf1h);
    prep_xh<<<(int)((((size_t)B_SZ * 8192 + 64) / 4 + 255) / 256), 256, 0, stream>>>(x, xh);
    d0_kernel<<<B_SZ, 256, 0, stream>>>(x, Wp, bp, d0);

    // ---- chunked pipeline ----------------------------------------------
    for (int c = 0; c < nchunk; ++c) {
        const size_t b0 = (size_t)c * CB;
        // pointwise: in rows = xh[b][ (l+1)*64 .. ] -> offset +64
        mfma_layer<128, L0_, 64, 64, 72><<<CB, 256, 0, stream>>>(
            xh + b0 * 8192 + 64, 8192, wp1t, d0 + b0 * NCH, NCH, buf0);
        mfma_layer<L0_, L1_, 256, 768, 264><<<CB, 256, 0, stream>>>(
            buf0, (long)L0_ * NCH, wct1, b1, 0, buf1);
        mfma_layer<L1_, L2_, 256, 768, 264><<<CB, 256, 0, stream>>>(
            buf1, (long)L1_ * NCH, wct2, b2, 0, buf0);
        mfma_layer<L2_, L3_, 256, 768, 264><<<CB, 256, 0, stream>>>(
            buf0, (long)L2_ * NCH, wct3, b3, 0, buf1);
        // transpose h3 -> FC-ready layout (into buf0, which is now free)
        h3t_kernel<<<CB, 256, 0, stream>>>(buf1, buf0);
        fc1_kernel<<<dim3(CB / 128, 4, SPLIT), 256, 0, stream>>>(buf0, wf1h, part, CB);
        fc1_reduce_kernel<<<CB * 2, 256, 0, stream>>>(part, bf1, h4 + b0 * F1_, CB);
    }

    fc2_kernel<<<B_SZ / 4, 256, 0, stream>>>(h4, Wf2, bf2, out);
}

// Round 4
// 1123.620 us; speedup vs baseline: 5.9415x; 1.0811x over previous
//
#include <hip/hip_runtime.h>

typedef _Float16 f16;
typedef _Float16 f16x8 __attribute__((ext_vector_type(8)));
typedef _Float16 f16x4 __attribute__((ext_vector_type(4)));
typedef float    f32x4 __attribute__((ext_vector_type(4)));

#define B_SZ   2048
#define CLEN   128
#define NCH    256
#define L0_    127
#define L1_    125
#define L2_    123
#define L3_    121
#define F1_    512
#define FCK    30976
#define SPLIT  22          // 968 K-chunks of 32 -> 44 per split
#define CPS    44

// ---------------------------------------------------------------------------
// prep: Wp[:, :, 1] -> fp16 wp1t[c][j]   (16384 elems)
// ---------------------------------------------------------------------------
__global__ __launch_bounds__(256) void prep_wp1t(const float* __restrict__ Wp,
                                                 f16* __restrict__ wp1t) {
    int idx = blockIdx.x * 256 + threadIdx.x;
    if (idx >= NCH * 64) return;
    int c = idx >> 6, j = idx & 63;
    wp1t[idx] = (f16)Wp[c * 128 + j * 2 + 1];
}

// prep: W[co][ci][k] -> fp16 wct[co][k*256+ci]   (196608 elems)
__global__ __launch_bounds__(256) void prep_wct(const float* __restrict__ W,
                                                f16* __restrict__ wct) {
    int idx = blockIdx.x * 256 + threadIdx.x;
    if (idx >= NCH * 768) return;
    int co = idx / 768, rem = idx - co * 768;
    int k = rem >> 8, ci = rem & 255;
    wct[idx] = (f16)W[((size_t)co * NCH + ci) * 3 + k];
}

// prep: Wf1[f][co*121+l] -> fp16 wf1h[f][l*256+co]  (K-permuted so FC1's A is
// conv3's [l][co] output directly — h3t transpose kernel eliminated)
__global__ __launch_bounds__(256) void prep_wf1k(const float* __restrict__ Wf1,
                                                 f16* __restrict__ wf1h) {
    __shared__ f16 t[NCH * 122];          // [co][l], pad 122 (odd dw stride)
    const int f = blockIdx.x, tid = threadIdx.x;
    const float* src = Wf1 + (size_t)f * FCK;
    for (int idx = tid; idx < FCK; idx += 256) {
        int co = idx / 121, l = idx - co * 121;
        t[co * 122 + l] = (f16)src[idx];
    }
    __syncthreads();
    f16* dst = wf1h + (size_t)f * FCK;
    for (int idx = tid; idx < FCK; idx += 256) {
        int l = idx >> 8, co = idx & 255;
        dst[idx] = t[co * 122 + l];
    }
}

// prep: x -> fp16 xh (2048*8192), + zero 64-elem pad
__global__ __launch_bounds__(256) void prep_xh(const float* __restrict__ x,
                                               f16* __restrict__ xh) {
    size_t g = (size_t)blockIdx.x * 256 + threadIdx.x;
    size_t N = (size_t)B_SZ * 8192;
    if (g * 4 >= N + 64) return;
    if (g * 4 < N) {
        float4 v = *(const float4*)(x + g * 4);
        f16x4 h = { (f16)v.x, (f16)v.y, (f16)v.z, (f16)v.w };
        *(f16x4*)(xh + g * 4) = h;
    } else {
        f16x4 z = { (f16)0.f, (f16)0.f, (f16)0.f, (f16)0.f };
        *(f16x4*)(xh + g * 4) = z;
    }
}

// ---------------------------------------------------------------------------
// d0[b][c] = bp[c] + sum_j x[b][j] * Wp[c][j][0]   (fp32, exact path)
// ---------------------------------------------------------------------------
__global__ __launch_bounds__(256) void d0_kernel(const float* __restrict__ x,
                                                 const float* __restrict__ Wp,
                                                 const float* __restrict__ bp,
                                                 float* __restrict__ d0) {
    __shared__ float wp0s[NCH * 65];
    __shared__ float x0[64];
    const int b = blockIdx.x, tid = threadIdx.x;
    for (int u = tid; u < NCH * 64; u += 256) {
        int c = u >> 6, j = u & 63;
        wp0s[c * 65 + j] = Wp[c * 128 + j * 2];
    }
    if (tid < 64) x0[tid] = x[(size_t)b * 8192 + tid];
    __syncthreads();
    const int c = tid;
    float acc = bp[c];
#pragma unroll
    for (int j = 0; j < 64; ++j) acc = fmaf(x0[j], wp0s[c * 65 + j], acc);
    d0[(size_t)b * NCH + c] = acc;
}

// ---------------------------------------------------------------------------
// Unified MFMA layer: out[b][l][co] = relu(extra + sum_{k,ci} in[b][l+k][ci]*W)
//  - block = one b, 256 threads (4 waves, 2x2 of 64l x 128co)
//  - A (activations) from padded LDS; B (weights [co][KT]) from global/L2,
//    register double-buffered one K-step ahead (the Round-3 stall fix)
// ---------------------------------------------------------------------------
template <int SROWS, int LOUT, int CIN, int KT, int PADC>
__global__ __launch_bounds__(256, 2) void mfma_layer(const f16* __restrict__ in,
                                                     long in_bstride,
                                                     const f16* __restrict__ wt,
                                                     const float* __restrict__ extra,
                                                     long e_bstride,
                                                     f16* __restrict__ out) {
    __shared__ f16 ins[130 * PADC];
    const int b = blockIdx.x;
    const int tid = threadIdx.x;
    const int lane = tid & 63, w = tid >> 6;
    const int wl0 = (w >> 1) * 64, wc0 = (w & 1) * 128;
    const int lr = lane & 15, lh = lane >> 4;

    // stage input tile (contiguous rows of CIN fp16)
    const f16* inb = in + (size_t)b * in_bstride;
    constexpr int UPR = CIN / 8;             // 16B units per row
    constexpr int USH = (CIN == 256) ? 5 : 3;
    constexpr int UMS = UPR - 1;
    for (int u = tid; u < SROWS * UPR; u += 256) {
        int row = u >> USH, sl = u & UMS;
        *(f16x8*)(ins + row * PADC + sl * 8) =
            *(const f16x8*)(inb + (size_t)row * CIN + sl * 8);
    }
    __syncthreads();

    f32x4 acc[4][8];
#pragma unroll
    for (int m = 0; m < 4; ++m)
#pragma unroll
        for (int n = 0; n < 8; ++n) acc[m][n] = (f32x4){0.f, 0.f, 0.f, 0.f};

    constexpr int KSTEPS = KT / 32;          // even for all instantiations
    constexpr int CSTEPS = CIN / 32;
    const f16* wb = wt + (size_t)(wc0 + lr) * KT + lh * 8;

    f16x8 bA[8], bB[8];
#pragma unroll
    for (int n = 0; n < 8; ++n) bA[n] = *(const f16x8*)(wb + n * 16 * KT);

#pragma unroll 1
    for (int ks = 0; ks < KSTEPS; ks += 2) {
        // even step: consume bA, prefetch bB for ks+1 (always valid)
        {
            const int k = ks / CSTEPS, ci0 = (ks % CSTEPS) * 32;
            f16x8 a[4];
#pragma unroll
            for (int m = 0; m < 4; ++m)
                a[m] = *(const f16x8*)(ins + (wl0 + 16 * m + lr + k) * PADC
                                       + ci0 + lh * 8);
            __builtin_amdgcn_s_setprio(1);
#pragma unroll
            for (int n = 0; n < 8; ++n) {
                bB[n] = *(const f16x8*)(wb + n * 16 * KT + (ks + 1) * 32);
#pragma unroll
                for (int m = 0; m < 4; ++m)
                    acc[m][n] = __builtin_amdgcn_mfma_f32_16x16x32_f16(
                        a[m], bA[n], acc[m][n], 0, 0, 0);
            }
            __builtin_amdgcn_s_setprio(0);
        }
        // odd step: consume bB, prefetch bA for ks+2 (clamped dummy on last)
        {
            const int ks1 = ks + 1;
            const int k = ks1 / CSTEPS, ci0 = (ks1 % CSTEPS) * 32;
            const int ks2 = (ks + 2 < KSTEPS) ? (ks + 2) : 0;
            f16x8 a[4];
#pragma unroll
            for (int m = 0; m < 4; ++m)
                a[m] = *(const f16x8*)(ins + (wl0 + 16 * m + lr + k) * PADC
                                       + ci0 + lh * 8);
            __builtin_amdgcn_s_setprio(1);
#pragma unroll
            for (int n = 0; n < 8; ++n) {
                bA[n] = *(const f16x8*)(wb + n * 16 * KT + ks2 * 32);
#pragma unroll
                for (int m = 0; m < 4; ++m)
                    acc[m][n] = __builtin_amdgcn_mfma_f32_16x16x32_f16(
                        a[m], bB[n], acc[m][n], 0, 0, 0);
            }
            __builtin_amdgcn_s_setprio(0);
        }
    }

    // epilogue: +extra, relu, fp16 store to [b][l][256]
    const float* ep = extra + (size_t)b * e_bstride;
    f16* ob = out + (size_t)b * LOUT * NCH;
#pragma unroll
    for (int n = 0; n < 8; ++n) {
        const int co = wc0 + 16 * n + lr;
        const float e = ep[co];
#pragma unroll
        for (int m = 0; m < 4; ++m) {
#pragma unroll
            for (int r = 0; r < 4; ++r) {
                const int l = wl0 + 16 * m + lh * 4 + r;
                if (l < LOUT) {
                    float v = fmaxf(acc[m][n][r] + e, 0.f);
                    ob[(size_t)l * NCH + co] = (f16)v;
                }
            }
        }
    }
}

// ---------------------------------------------------------------------------
// FC1 MFMA: part[sp][b_local][f] over split sp's K-range (fp32 partials)
// tile 128b x 128f, K-chunk 32, 4 waves 2x2 of 64x64
// ---------------------------------------------------------------------------
__global__ __launch_bounds__(256, 2) void fc1_kernel(const f16* __restrict__ A,
                                                     const f16* __restrict__ Bw,
                                                     float* __restrict__ part,
                                                     int CB) {
    __shared__ f16 As[128 * 40];
    __shared__ f16 Bs[128 * 40];
    const int m0 = blockIdx.x * 128, n0 = blockIdx.y * 128, sp = blockIdx.z;
    const int tid = threadIdx.x;
    const int lane = tid & 63, w = tid >> 6;
    const int wb0 = (w >> 1) * 64, wf0 = (w & 1) * 64;
    const int lr = lane & 15, lh = lane >> 4;

    f32x4 acc[4][4];
#pragma unroll
    for (int m = 0; m < 4; ++m)
#pragma unroll
        for (int n = 0; n < 4; ++n) acc[m][n] = (f32x4){0.f, 0.f, 0.f, 0.f};

    for (int it = 0; it < CPS; ++it) {
        const int k0 = (sp * CPS + it) * 32;
        __syncthreads();
        for (int u = tid; u < 512; u += 256) {
            int row = u >> 2, sl = u & 3;
            *(f16x8*)(As + row * 40 + sl * 8) =
                *(const f16x8*)(A + (size_t)(m0 + row) * FCK + k0 + sl * 8);
            *(f16x8*)(Bs + row * 40 + sl * 8) =
                *(const f16x8*)(Bw + (size_t)(n0 + row) * FCK + k0 + sl * 8);
        }
        __syncthreads();
        f16x8 a[4], bf[4];
#pragma unroll
        for (int m = 0; m < 4; ++m)
            a[m] = *(const f16x8*)(As + (wb0 + 16 * m + lr) * 40 + lh * 8);
#pragma unroll
        for (int n = 0; n < 4; ++n)
            bf[n] = *(const f16x8*)(Bs + (wf0 + 16 * n + lr) * 40 + lh * 8);
        __builtin_amdgcn_s_setprio(1);
#pragma unroll
        for (int m = 0; m < 4; ++m)
#pragma unroll
            for (int n = 0; n < 4; ++n)
                acc[m][n] = __builtin_amdgcn_mfma_f32_16x16x32_f16(a[m], bf[n],
                                                                   acc[m][n], 0, 0, 0);
        __builtin_amdgcn_s_setprio(0);
    }

#pragma unroll
    for (int m = 0; m < 4; ++m)
#pragma unroll
        for (int n = 0; n < 4; ++n)
#pragma unroll
            for (int r = 0; r < 4; ++r) {
                const int bl = m0 + wb0 + 16 * m + lh * 4 + r;
                const int f  = n0 + wf0 + 16 * n + lr;
                part[((size_t)sp * CB + bl) * F1_ + f] = acc[m][n][r];
            }
}

// h4[m,f] = relu(bf1[f] + sum_sp part[sp][m][f])
__global__ __launch_bounds__(256) void fc1_reduce_kernel(const float* __restrict__ part,
                                                         const float* __restrict__ bf1,
                                                         float* __restrict__ h4,
                                                         int CB) {
    int idx = blockIdx.x * 256 + threadIdx.x;
    int f = idx & (F1_ - 1);
    float s = bf1[f];
#pragma unroll
    for (int sp = 0; sp < SPLIT; ++sp)
        s += part[(size_t)sp * CB * F1_ + idx];
    h4[idx] = fmaxf(s, 0.f);
}

// out[b] = bf2 + h4[b,:] . Wf2   (fp32)
__global__ __launch_bounds__(256) void fc2_kernel(const float* __restrict__ h4,
                                                  const float* __restrict__ Wf2,
                                                  const float* __restrict__ bf2,
                                                  float* __restrict__ out) {
    const int b    = blockIdx.x * 4 + (threadIdx.x >> 6);
    const int lane = threadIdx.x & 63;
    float s = 0.f;
#pragma unroll
    for (int i = 0; i < 8; ++i) s = fmaf(h4[(size_t)b * F1_ + lane + 64 * i],
                                         Wf2[lane + 64 * i], s);
#pragma unroll
    for (int o = 32; o > 0; o >>= 1) s += __shfl_xor(s, o);
    if (lane == 0) out[b] = s + bf2[0];
}

// ---------------------------------------------------------------------------
extern "C" void kernel_launch(void* const* d_in, const int* in_sizes, int n_in,
                              void* d_out, int out_size, void* d_ws, size_t ws_size,
                              hipStream_t stream) {
    const float* x   = (const float*)d_in[0];
    const float* Wp  = (const float*)d_in[1];
    const float* bp  = (const float*)d_in[2];
    const float* W1  = (const float*)d_in[3];
    const float* b1  = (const float*)d_in[4];
    const float* W2  = (const float*)d_in[5];
    const float* b2  = (const float*)d_in[6];
    const float* W3  = (const float*)d_in[7];
    const float* b3  = (const float*)d_in[8];
    const float* Wf1 = (const float*)d_in[9];
    const float* bf1 = (const float*)d_in[10];
    const float* Wf2 = (const float*)d_in[11];
    const float* bf2 = (const float*)d_in[12];
    float* out = (float*)d_out;

    // ---- workspace layout (256B-aligned chunks) ------------------------
    char* base = (char*)d_ws;
    size_t off = 0;
    auto alloc = [&](size_t bytes) {
        size_t o = off; off = (off + bytes + 255) & ~(size_t)255; return o;
    };
    const size_t o_wp1t = alloc((size_t)NCH * 64 * 2);
    const size_t o_wct1 = alloc((size_t)NCH * 768 * 2);
    const size_t o_wct2 = alloc((size_t)NCH * 768 * 2);
    const size_t o_wct3 = alloc((size_t)NCH * 768 * 2);
    const size_t o_wf1h = alloc((size_t)F1_ * FCK * 2);
    const size_t o_xh   = alloc(((size_t)B_SZ * 8192 + 64) * 2);
    const size_t o_d0   = alloc((size_t)B_SZ * NCH * 4);
    const size_t o_h4   = alloc((size_t)B_SZ * F1_ * 4);
    const size_t fixed  = off;

    int CB = 0;
    const int cand[5] = {2048, 1024, 512, 256, 128};
    for (int i = 0; i < 5; ++i) {
        size_t c = (size_t)cand[i];
        size_t need = fixed
            + (((size_t)SPLIT * c * F1_ * 4 + 255) & ~(size_t)255)   // part
            + ((c * (size_t)L0_ * NCH * 2 + 255) & ~(size_t)255)     // buf0
            + ((c * (size_t)L1_ * NCH * 2 + 255) & ~(size_t)255);    // buf1
        if (need <= ws_size) { CB = cand[i]; break; }
    }
    if (CB == 0) return;
    const int nchunk = B_SZ / CB;

    const size_t o_part = alloc((size_t)SPLIT * CB * F1_ * 4);
    const size_t o_buf0 = alloc((size_t)CB * L0_ * NCH * 2);
    const size_t o_buf1 = alloc((size_t)CB * L1_ * NCH * 2);

    f16*   wp1t = (f16*)(base + o_wp1t);
    f16*   wct1 = (f16*)(base + o_wct1);
    f16*   wct2 = (f16*)(base + o_wct2);
    f16*   wct3 = (f16*)(base + o_wct3);
    f16*   wf1h = (f16*)(base + o_wf1h);
    f16*   xh   = (f16*)(base + o_xh);
    float* d0   = (float*)(base + o_d0);
    float* h4   = (float*)(base + o_h4);
    float* part = (float*)(base + o_part);
    f16*   buf0 = (f16*)(base + o_buf0);
    f16*   buf1 = (f16*)(base + o_buf1);

    // ---- preps ---------------------------------------------------------
    prep_wp1t<<<64, 256, 0, stream>>>(Wp, wp1t);
    prep_wct<<<768, 256, 0, stream>>>(W1, wct1);
    prep_wct<<<768, 256, 0, stream>>>(W2, wct2);
    prep_wct<<<768, 256, 0, stream>>>(W3, wct3);
    prep_wf1k<<<F1_, 256, 0, stream>>>(Wf1, wf1h);
    prep_xh<<<(int)((((size_t)B_SZ * 8192 + 64) / 4 + 255) / 256), 256, 0, stream>>>(x, xh);
    d0_kernel<<<B_SZ, 256, 0, stream>>>(x, Wp, bp, d0);

    // ---- chunked pipeline ----------------------------------------------
    for (int c = 0; c < nchunk; ++c) {
        const size_t b0 = (size_t)c * CB;
        // pointwise: in rows = xh[b][ (l+1)*64 .. ] -> offset +64
        mfma_layer<128, L0_, 64, 64, 72><<<CB, 256, 0, stream>>>(
            xh + b0 * 8192 + 64, 8192, wp1t, d0 + b0 * NCH, NCH, buf0);
        mfma_layer<L0_, L1_, 256, 768, 264><<<CB, 256, 0, stream>>>(
            buf0, (long)L0_ * NCH, wct1, b1, 0, buf1);
        mfma_layer<L1_, L2_, 256, 768, 264><<<CB, 256, 0, stream>>>(
            buf1, (long)L1_ * NCH, wct2, b2, 0, buf0);
        mfma_layer<L2_, L3_, 256, 768, 264><<<CB, 256, 0, stream>>>(
            buf0, (long)L2_ * NCH, wct3, b3, 0, buf1);
        // conv3 output [l][co] IS the FC1 A layout (wf1h K-permuted at prep)
        fc1_kernel<<<dim3(CB / 128, 4, SPLIT), 256, 0, stream>>>(buf1, wf1h, part, CB);
        fc1_reduce_kernel<<<CB * 2, 256, 0, stream>>>(part, bf1, h4 + b0 * F1_, CB);
    }

    fc2_kernel<<<B_SZ / 4, 256, 0, stream>>>(h4, Wf2, bf2, out);
}

// Round 5
// 955.805 us; speedup vs baseline: 6.9847x; 1.1756x over previous
//
#include <hip/hip_runtime.h>

typedef _Float16 f16;
typedef _Float16 f16x8 __attribute__((ext_vector_type(8)));
typedef _Float16 f16x4 __attribute__((ext_vector_type(4)));
typedef float    f32x4 __attribute__((ext_vector_type(4)));

#define B_SZ   2048
#define NCH    256
#define L0_    127
#define L1_    125
#define L2_    123
#define L3_    121
#define F1_    512
#define FCK    30976
#define SPLIT  22          // 968 K-chunks of 32 -> 44 per split
#define CPS    44

// async global->LDS, 16B per lane; dest = wave-uniform base + lane*16
__device__ __forceinline__ void gl16(const f16* g, f16* l) {
    __builtin_amdgcn_global_load_lds(
        (const __attribute__((address_space(1))) void*)g,
        (__attribute__((address_space(3))) void*)l, 16, 0, 0);
}

// ---------------------------------------------------------------------------
// prep: pointwise weights wpw[c][0:64]=Wp[c][:,1], wpw[c][64:128]=Wp[c][:,0]
// (K=128 GEMM folds the l=0 term; bias epilogue = bp)
// ---------------------------------------------------------------------------
__global__ __launch_bounds__(256) void prep_wpw(const float* __restrict__ Wp,
                                                f16* __restrict__ wpw) {
    int idx = blockIdx.x * 256 + threadIdx.x;
    if (idx >= NCH * 128) return;
    int c = idx >> 7, j = idx & 127;
    float v = (j < 64) ? Wp[c * 128 + j * 2 + 1] : Wp[c * 128 + (j - 64) * 2];
    wpw[idx] = (f16)v;
}

// prep: W[co][ci][k] -> fp16 wct[co][k*256+ci]
__global__ __launch_bounds__(256) void prep_wct(const float* __restrict__ W,
                                                f16* __restrict__ wct) {
    int idx = blockIdx.x * 256 + threadIdx.x;
    if (idx >= NCH * 768) return;
    int co = idx / 768, rem = idx - co * 768;
    int k = rem >> 8, ci = rem & 255;
    wct[idx] = (f16)W[((size_t)co * NCH + ci) * 3 + k];
}

// prep: Wf1[f][co*121+l] -> fp16 wf1h[f][l*256+co] (K-permuted: conv3 output
// [l][co] feeds FC1 directly)
__global__ __launch_bounds__(256) void prep_wf1k(const float* __restrict__ Wf1,
                                                 f16* __restrict__ wf1h) {
    __shared__ f16 t[NCH * 122];
    const int f = blockIdx.x, tid = threadIdx.x;
    const float* src = Wf1 + (size_t)f * FCK;
    for (int idx = tid; idx < FCK; idx += 256) {
        int co = idx / 121, l = idx - co * 121;
        t[co * 122 + l] = (f16)src[idx];
    }
    __syncthreads();
    f16* dst = wf1h + (size_t)f * FCK;
    for (int idx = tid; idx < FCK; idx += 256) {
        int l = idx >> 8, co = idx & 255;
        dst[idx] = t[co * 122 + l];
    }
}

// prep: x -> fp16 xh (2048*8192) + 64-elem zero pad
__global__ __launch_bounds__(256) void prep_xh(const float* __restrict__ x,
                                               f16* __restrict__ xh) {
    size_t g = (size_t)blockIdx.x * 256 + threadIdx.x;
    size_t N = (size_t)B_SZ * 8192;
    if (g * 4 >= N + 64) return;
    if (g * 4 < N) {
        float4 v = *(const float4*)(x + g * 4);
        f16x4 h = { (f16)v.x, (f16)v.y, (f16)v.z, (f16)v.w };
        *(f16x4*)(xh + g * 4) = h;
    } else {
        f16x4 z = { (f16)0.f, (f16)0.f, (f16)0.f, (f16)0.f };
        *(f16x4*)(xh + g * 4) = z;
    }
}

// ---------------------------------------------------------------------------
// Unified 2-phase conv/pointwise kernel.
//   out[b][l][co] = relu(extra + sum_{k,ci} in[b][l+k][ci] * wt[co][k*CIN+ci])
// Block = (b, 64-l half), 256 threads = 4 waves, wave tile 64l x 64co.
// Weights double-buffered in LDS via global_load_lds (swizzled source,
// swizzled read -> balanced banks). Input tile reg-staged once (padded LDS).
// One __syncthreads per K-step = the 2-phase pipeline (vmcnt drained there).
// ---------------------------------------------------------------------------
template <int CIN, int KSTEPS, int PADC, int LOUT, int SROWS, bool ISPW>
__global__ __launch_bounds__(256, 2) void conv2ph(
        const f16* __restrict__ in, long in_bstride,
        const f16* __restrict__ x0base,
        const f16* __restrict__ wt,
        const float* __restrict__ extra, long e_bstride,
        f16* __restrict__ out) {
    constexpr int KT     = KSTEPS * 32;
    constexpr int CSTEPS = CIN / 32;
    constexpr int UPR    = CIN / 8;             // 16B units per input row
    constexpr int LINV   = ISPW ? LOUT : (LOUT + 2);
    constexpr int ROWST  = ISPW ? 64 : CIN;     // global input row stride

    __shared__ f16 ins[SROWS * PADC];
    __shared__ f16 wlds[2 * 8192];              // 2 x (256co x 32k)

    const int b    = blockIdx.x;
    const int lh0  = blockIdx.y * 64;
    const int tid  = threadIdx.x;
    const int lane = tid & 63, w = tid >> 6;
    const int wc0  = w * 64;
    const int lr   = lane & 15, lh = lane >> 4;

    // prologue: issue weight chunk 0 (async), then stage input tile
#pragma unroll
    for (int j = 0; j < 4; ++j) {
        int u = j * 256 + w * 64 + lane;
        int row = u >> 2, cu = u & 3;
        int cs = cu ^ (row & 3);
        gl16(wt + (size_t)row * KT + cs * 8,
             wlds + (size_t)(j * 256 + w * 64) * 8);
    }
    const f16* inb = in + (size_t)b * in_bstride;
    for (int u = tid; u < SROWS * UPR; u += 256) {
        int r = u / UPR, sl = u % UPR;
        int sr = lh0 + r; if (sr > LINV - 1) sr = LINV - 1;
        const f16* src;
        if (ISPW && sl >= 8)
            src = x0base + (size_t)b * 8192 + (sl - 8) * 8;   // x0 block
        else
            src = inb + (size_t)sr * ROWST + sl * 8;
        *(f16x8*)(ins + r * PADC + sl * 8) = *(const f16x8*)src;
    }
    __syncthreads();

    f32x4 acc[4][4];
#pragma unroll
    for (int m = 0; m < 4; ++m)
#pragma unroll
        for (int n = 0; n < 4; ++n) acc[m][n] = (f32x4){0.f, 0.f, 0.f, 0.f};

    int cur = 0;
#pragma unroll 1
    for (int ks = 0; ks < KSTEPS; ++ks) {
        if (ks + 1 < KSTEPS) {                  // stage next chunk (async)
#pragma unroll
            for (int j = 0; j < 4; ++j) {
                int u = j * 256 + w * 64 + lane;
                int row = u >> 2, cu = u & 3;
                int cs = cu ^ (row & 3);
                gl16(wt + (size_t)row * KT + (ks + 1) * 32 + cs * 8,
                     wlds + (cur ^ 1) * 8192 + (size_t)(j * 256 + w * 64) * 8);
            }
        }
        const int k = ks / CSTEPS, ci0 = (ks % CSTEPS) * 32;
        f16x8 a[4], bfr[4];
#pragma unroll
        for (int m = 0; m < 4; ++m)
            a[m] = *(const f16x8*)(ins + (16 * m + lr + k) * PADC + ci0 + lh * 8);
#pragma unroll
        for (int n = 0; n < 4; ++n)
            bfr[n] = *(const f16x8*)(wlds + cur * 8192
                        + (size_t)((wc0 + 16 * n + lr) * 4 + (lh ^ (lr & 3))) * 8);
#pragma unroll
        for (int m = 0; m < 4; ++m)
#pragma unroll
            for (int n = 0; n < 4; ++n)
                acc[m][n] = __builtin_amdgcn_mfma_f32_16x16x32_f16(
                    a[m], bfr[n], acc[m][n], 0, 0, 0);
        __syncthreads();                        // drains vmcnt too (stage done)
        cur ^= 1;
    }

    // epilogue: +extra, relu, fp16 store to [b][l][256]
    const float* ep = extra + (size_t)b * e_bstride;
    f16* ob = out + (size_t)b * LOUT * NCH;
#pragma unroll
    for (int n = 0; n < 4; ++n) {
        const int co = wc0 + 16 * n + lr;
        const float e = ep[co];
#pragma unroll
        for (int m = 0; m < 4; ++m)
#pragma unroll
            for (int r = 0; r < 4; ++r) {
                const int l = lh0 + 16 * m + lh * 4 + r;
                if (l < LOUT) {
                    float v = fmaxf(acc[m][n][r] + e, 0.f);
                    ob[(size_t)l * NCH + co] = (f16)v;
                }
            }
    }
}

// ---------------------------------------------------------------------------
// FC1, same 2-phase global_load_lds structure.
// Block tile 128b x 128f, waves 2x2 (64x64), K-chunk 32, split-K partials.
// ---------------------------------------------------------------------------
__global__ __launch_bounds__(256, 2) void fc1_2ph(const f16* __restrict__ A,
                                                  const f16* __restrict__ Bw,
                                                  float* __restrict__ part,
                                                  int CB) {
    __shared__ f16 Asl[2 * 4096];
    __shared__ f16 Bsl[2 * 4096];
    const int m0 = blockIdx.x * 128, n0 = blockIdx.y * 128, sp = blockIdx.z;
    const int tid  = threadIdx.x;
    const int lane = tid & 63, w = tid >> 6;
    const int wb0  = (w >> 1) * 64, wf0 = (w & 1) * 64;
    const int lr   = lane & 15, lh = lane >> 4;
    const int k0s  = sp * CPS * 32;

    auto stage = [&](int buf, int k0) {
#pragma unroll
        for (int j = 0; j < 2; ++j) {
            int u = j * 256 + w * 64 + lane;
            int row = u >> 2, cu = u & 3;
            int cs = cu ^ (row & 3);
            gl16(A + (size_t)(m0 + row) * FCK + k0 + cs * 8,
                 Asl + buf * 4096 + (size_t)(j * 256 + w * 64) * 8);
            gl16(Bw + (size_t)(n0 + row) * FCK + k0 + cs * 8,
                 Bsl + buf * 4096 + (size_t)(j * 256 + w * 64) * 8);
        }
    };

    f32x4 acc[4][4];
#pragma unroll
    for (int m = 0; m < 4; ++m)
#pragma unroll
        for (int n = 0; n < 4; ++n) acc[m][n] = (f32x4){0.f, 0.f, 0.f, 0.f};

    stage(0, k0s);
    __syncthreads();
    int cur = 0;
#pragma unroll 1
    for (int it = 0; it < CPS; ++it) {
        if (it + 1 < CPS) stage(cur ^ 1, k0s + (it + 1) * 32);
        f16x8 a[4], bf[4];
#pragma unroll
        for (int m = 0; m < 4; ++m)
            a[m] = *(const f16x8*)(Asl + cur * 4096
                      + (size_t)((wb0 + 16 * m + lr) * 4 + (lh ^ (lr & 3))) * 8);
#pragma unroll
        for (int n = 0; n < 4; ++n)
            bf[n] = *(const f16x8*)(Bsl + cur * 4096
                      + (size_t)((wf0 + 16 * n + lr) * 4 + (lh ^ (lr & 3))) * 8);
#pragma unroll
        for (int m = 0; m < 4; ++m)
#pragma unroll
            for (int n = 0; n < 4; ++n)
                acc[m][n] = __builtin_amdgcn_mfma_f32_16x16x32_f16(
                    a[m], bf[n], acc[m][n], 0, 0, 0);
        __syncthreads();
        cur ^= 1;
    }

#pragma unroll
    for (int m = 0; m < 4; ++m)
#pragma unroll
        for (int n = 0; n < 4; ++n)
#pragma unroll
            for (int r = 0; r < 4; ++r) {
                const int bl = m0 + wb0 + 16 * m + lh * 4 + r;
                const int f  = n0 + wf0 + 16 * n + lr;
                part[((size_t)sp * CB + bl) * F1_ + f] = acc[m][n][r];
            }
}

// h4[m,f] = relu(bf1[f] + sum_sp part[sp][m][f])
__global__ __launch_bounds__(256) void fc1_reduce_kernel(const float* __restrict__ part,
                                                         const float* __restrict__ bf1,
                                                         float* __restrict__ h4,
                                                         int CB) {
    int idx = blockIdx.x * 256 + threadIdx.x;
    int f = idx & (F1_ - 1);
    float s = bf1[f];
#pragma unroll
    for (int sp = 0; sp < SPLIT; ++sp)
        s += part[(size_t)sp * CB * F1_ + idx];
    h4[idx] = fmaxf(s, 0.f);
}

// out[b] = bf2 + h4[b,:] . Wf2
__global__ __launch_bounds__(256) void fc2_kernel(const float* __restrict__ h4,
                                                  const float* __restrict__ Wf2,
                                                  const float* __restrict__ bf2,
                                                  float* __restrict__ out) {
    const int b    = blockIdx.x * 4 + (threadIdx.x >> 6);
    const int lane = threadIdx.x & 63;
    float s = 0.f;
#pragma unroll
    for (int i = 0; i < 8; ++i) s = fmaf(h4[(size_t)b * F1_ + lane + 64 * i],
                                         Wf2[lane + 64 * i], s);
#pragma unroll
    for (int o = 32; o > 0; o >>= 1) s += __shfl_xor(s, o);
    if (lane == 0) out[b] = s + bf2[0];
}

// ---------------------------------------------------------------------------
extern "C" void kernel_launch(void* const* d_in, const int* in_sizes, int n_in,
                              void* d_out, int out_size, void* d_ws, size_t ws_size,
                              hipStream_t stream) {
    const float* x   = (const float*)d_in[0];
    const float* Wp  = (const float*)d_in[1];
    const float* bp  = (const float*)d_in[2];
    const float* W1  = (const float*)d_in[3];
    const float* b1  = (const float*)d_in[4];
    const float* W2  = (const float*)d_in[5];
    const float* b2  = (const float*)d_in[6];
    const float* W3  = (const float*)d_in[7];
    const float* b3  = (const float*)d_in[8];
    const float* Wf1 = (const float*)d_in[9];
    const float* bf1 = (const float*)d_in[10];
    const float* Wf2 = (const float*)d_in[11];
    const float* bf2 = (const float*)d_in[12];
    float* out = (float*)d_out;

    // ---- workspace layout ----------------------------------------------
    char* base = (char*)d_ws;
    size_t off = 0;
    auto alloc = [&](size_t bytes) {
        size_t o = off; off = (off + bytes + 255) & ~(size_t)255; return o;
    };
    const size_t o_wpw  = alloc((size_t)NCH * 128 * 2);
    const size_t o_wct1 = alloc((size_t)NCH * 768 * 2);
    const size_t o_wct2 = alloc((size_t)NCH * 768 * 2);
    const size_t o_wct3 = alloc((size_t)NCH * 768 * 2);
    const size_t o_wf1h = alloc((size_t)F1_ * FCK * 2);
    const size_t o_xh   = alloc(((size_t)B_SZ * 8192 + 64) * 2);
    const size_t o_h4   = alloc((size_t)B_SZ * F1_ * 4);
    const size_t fixed  = off;

    int CB = 0;
    const int cand[5] = {2048, 1024, 512, 256, 128};
    for (int i = 0; i < 5; ++i) {
        size_t c = (size_t)cand[i];
        size_t need = fixed
            + (((size_t)SPLIT * c * F1_ * 4 + 255) & ~(size_t)255)   // part
            + ((c * (size_t)L0_ * NCH * 2 + 255) & ~(size_t)255)     // buf0
            + ((c * (size_t)L1_ * NCH * 2 + 255) & ~(size_t)255);    // buf1
        if (need <= ws_size) { CB = cand[i]; break; }
    }
    if (CB == 0) return;
    const int nchunk = B_SZ / CB;

    const size_t o_part = alloc((size_t)SPLIT * CB * F1_ * 4);
    const size_t o_buf0 = alloc((size_t)CB * L0_ * NCH * 2);
    const size_t o_buf1 = alloc((size_t)CB * L1_ * NCH * 2);

    f16*   wpw  = (f16*)(base + o_wpw);
    f16*   wct1 = (f16*)(base + o_wct1);
    f16*   wct2 = (f16*)(base + o_wct2);
    f16*   wct3 = (f16*)(base + o_wct3);
    f16*   wf1h = (f16*)(base + o_wf1h);
    f16*   xh   = (f16*)(base + o_xh);
    float* h4   = (float*)(base + o_h4);
    float* part = (float*)(base + o_part);
    f16*   buf0 = (f16*)(base + o_buf0);
    f16*   buf1 = (f16*)(base + o_buf1);

    // ---- preps ---------------------------------------------------------
    prep_wpw<<<128, 256, 0, stream>>>(Wp, wpw);
    prep_wct<<<768, 256, 0, stream>>>(W1, wct1);
    prep_wct<<<768, 256, 0, stream>>>(W2, wct2);
    prep_wct<<<768, 256, 0, stream>>>(W3, wct3);
    prep_wf1k<<<F1_, 256, 0, stream>>>(Wf1, wf1h);
    prep_xh<<<(int)((((size_t)B_SZ * 8192 + 64) / 4 + 255) / 256), 256, 0, stream>>>(x, xh);

    // ---- chunked pipeline ----------------------------------------------
    for (int c = 0; c < nchunk; ++c) {
        const size_t b0 = (size_t)c * CB;
        // pointwise as K=128 GEMM: rows = xh[b][(l+1)*64..], + x0 tile
        conv2ph<128, 4, 136, L0_, 64, true><<<dim3(CB, 2), 256, 0, stream>>>(
            xh + b0 * 8192 + 64, 8192, xh + b0 * 8192, wpw, bp, 0, buf0);
        conv2ph<256, 24, 264, L1_, 66, false><<<dim3(CB, 2), 256, 0, stream>>>(
            buf0, (long)L0_ * NCH, nullptr, wct1, b1, 0, buf1);
        conv2ph<256, 24, 264, L2_, 66, false><<<dim3(CB, 2), 256, 0, stream>>>(
            buf1, (long)L1_ * NCH, nullptr, wct2, b2, 0, buf0);
        conv2ph<256, 24, 264, L3_, 66, false><<<dim3(CB, 2), 256, 0, stream>>>(
            buf0, (long)L2_ * NCH, nullptr, wct3, b3, 0, buf1);
        // conv3 output [l][co] IS the FC1 A layout (wf1h K-permuted at prep)
        fc1_2ph<<<dim3(CB / 128, 4, SPLIT), 256, 0, stream>>>(buf1, wf1h, part, CB);
        fc1_reduce_kernel<<<CB * 2, 256, 0, stream>>>(part, bf1, h4 + b0 * F1_, CB);
    }

    fc2_kernel<<<B_SZ / 4, 256, 0, stream>>>(h4, Wf2, bf2, out);
}